// Round 5
// baseline (576.438 us; speedup 1.0000x reference)
//
#include <hip/hip_runtime.h>
#include <hip/hip_bf16.h>

typedef __bf16 bf16;
typedef __bf16 v8bf __attribute__((ext_vector_type(8)));
typedef __bf16 v4bf __attribute__((ext_vector_type(4)));
typedef float  v4f  __attribute__((ext_vector_type(4)));

#define DEVI __device__ __forceinline__

constexpr int Bc   = 4;
constexpr int Tc   = 2048;
constexpr int Dc   = 768;
constexpr int Hc   = 12;
constexpr int HDc  = 64;
constexpr int MLPc = 3072;
constexpr int QKVc = 2304;    // 3*D
constexpr int BTc  = Bc * Tc; // 8192 rows

DEVI float b2f(bf16 x) { return (float)x; }
DEVI bf16  f2b(float x) { return (bf16)x; }

// async global->LDS, 16B per lane; lds dest = wave-uniform base + lane*16
#define GLDS(gp, lp) __builtin_amdgcn_global_load_lds( \
    (const __attribute__((address_space(1))) void*)(gp), \
    (__attribute__((address_space(3))) void*)(lp), 16, 0, 0)

// ---------------------------------------------------------------- fp32 -> bf16 weight conversion
__global__ __launch_bounds__(256) void cvt_kernel(
    const float* __restrict__ s, bf16* __restrict__ d, int n4)
{
    int i = blockIdx.x * 256 + threadIdx.x;
    if (i < n4) {
        float4 v = ((const float4*)s)[i];
        v4bf o = { f2b(v.x), f2b(v.y), f2b(v.z), f2b(v.w) };
        ((v4bf*)d)[i] = o;
    }
}

// ---------------------------------------------------------------- LayerNorm (fp32 in, bf16 out)
__global__ __launch_bounds__(256) void ln_kernel(
    const float* __restrict__ x, const float* __restrict__ g,
    const float* __restrict__ bt, bf16* __restrict__ out)
{
    const int row = blockIdx.x;
    const int t = threadIdx.x;
    const float* xr = x + (size_t)row * Dc;
    float v[3];
    v[0] = xr[t];
    v[1] = xr[t + 256];
    v[2] = xr[t + 512];
    float s = v[0] + v[1] + v[2];
    float s2 = v[0]*v[0] + v[1]*v[1] + v[2]*v[2];
    #pragma unroll
    for (int off = 32; off > 0; off >>= 1) {
        s  += __shfl_down(s, off);
        s2 += __shfl_down(s2, off);
    }
    __shared__ float red[8];
    const int wave = t >> 6, lane = t & 63;
    if (lane == 0) { red[wave] = s; red[4 + wave] = s2; }
    __syncthreads();
    s  = red[0] + red[1] + red[2] + red[3];
    s2 = red[4] + red[5] + red[6] + red[7];
    const float mean = s * (1.0f / Dc);
    const float var  = s2 * (1.0f / Dc) - mean * mean;
    const float rstd = rsqrtf(var + 1e-5f);
    bf16* orow = out + (size_t)row * Dc;
    #pragma unroll
    for (int i = 0; i < 3; i++) {
        int c = t + i * 256;
        orow[c] = f2b((v[i] - mean) * rstd * g[c] + bt[c]);
    }
}

// ---------------------------------------------------------------- GEMM (C = A @ B^T + bias, fused epilogues)
// A: [M][lda] bf16 row-major; Bw: [N rows][ldb] bf16. Uses K-range
// [blockIdx.z*Ks, blockIdx.z*Ks + Ks) of both (split-K via fp32 atomics).
// EPI_QKV: Cb = base of Qb|Kb|Vt triple buffer; Q/K stored [8192][768],
//          V stored transposed Vt[(b*H+h)*64+hd][t].
enum { EPI_QKV = 0, EPI_GELU_BF16 = 1, EPI_ATOMIC_F32 = 2 };

template <int EPI>
__global__ __launch_bounds__(256) void gemm_bt(
    const bf16* __restrict__ A, const bf16* __restrict__ Bw,
    const float* __restrict__ bias,
    bf16* __restrict__ Cb, float* __restrict__ Cf,
    int M, int N, int Ks, int lda, int ldb)
{
    __shared__ __align__(16) bf16 sA[128 * 64];
    __shared__ __align__(16) bf16 sB[128 * 64];
    const int t = threadIdx.x, wave = t >> 6, lane = t & 63;
    const int wm = wave & 1, wn = wave >> 1;
    const int m0 = blockIdx.y * 128, n0 = blockIdx.x * 128;
    const int koff = blockIdx.z * Ks;
    const bf16* Ag = A + (size_t)m0 * lda + koff;
    const bf16* Bg = Bw + (size_t)n0 * ldb + koff;

    v4f acc[4][4];
    #pragma unroll
    for (int i = 0; i < 4; i++)
        #pragma unroll
        for (int j = 0; j < 4; j++) acc[i][j] = (v4f)(0.0f);

    for (int k0 = 0; k0 < Ks; k0 += 64) {
        #pragma unroll
        for (int i = 0; i < 4; i++) {
            int c = i * 256 + t;                       // 16B chunk id
            GLDS(Ag + (size_t)(c >> 3) * lda + k0 + (c & 7) * 8,
                 &sA[(i * 256 + wave * 64) * 8]);
        }
        #pragma unroll
        for (int i = 0; i < 4; i++) {
            int c = i * 256 + t;
            GLDS(Bg + (size_t)(c >> 3) * ldb + k0 + (c & 7) * 8,
                 &sB[(i * 256 + wave * 64) * 8]);
        }
        __syncthreads();
        #pragma unroll
        for (int ks = 0; ks < 2; ks++) {
            const int kc = ks * 32 + (lane >> 4) * 8;
            v8bf a[4], b[4];
            #pragma unroll
            for (int mi = 0; mi < 4; mi++)
                a[mi] = *(const v8bf*)&sA[(wm * 64 + mi * 16 + (lane & 15)) * 64 + kc];
            #pragma unroll
            for (int ni = 0; ni < 4; ni++)
                b[ni] = *(const v8bf*)&sB[(wn * 64 + ni * 16 + (lane & 15)) * 64 + kc];
            #pragma unroll
            for (int mi = 0; mi < 4; mi++)
                #pragma unroll
                for (int ni = 0; ni < 4; ni++)
                    acc[mi][ni] = __builtin_amdgcn_mfma_f32_16x16x32_bf16(
                        a[mi], b[ni], acc[mi][ni], 0, 0, 0);
        }
        __syncthreads();
    }

    const int rq = lane >> 4, cn = lane & 15;
    #pragma unroll
    for (int mi = 0; mi < 4; mi++)
        #pragma unroll
        for (int ni = 0; ni < 4; ni++) {
            const int col = n0 + wn * 64 + ni * 16 + cn;
            const float bv = (bias && blockIdx.z == 0) ? bias[col] : 0.0f;
            if constexpr (EPI == EPI_QKV) {
                const int row0 = m0 + wm * 64 + mi * 16 + rq * 4;
                if (n0 < 2 * Dc) {
                    bf16* dst = Cb + (col < Dc ? 0 : (size_t)BTc * Dc);
                    const int cadj = col < Dc ? col : col - Dc;
                    #pragma unroll
                    for (int r = 0; r < 4; r++)
                        dst[(size_t)(row0 + r) * Dc + cadj] = f2b(acc[mi][ni][r] + bv);
                } else {
                    const int vcol = col - 2 * Dc;
                    const int hh = vcol >> 6, hd = vcol & 63;
                    const int bb = row0 >> 11, t0 = row0 & 2047;
                    v4bf pk;
                    #pragma unroll
                    for (int r = 0; r < 4; r++) pk[r] = f2b(acc[mi][ni][r] + bv);
                    *(v4bf*)(Cb + 2 * (size_t)BTc * Dc +
                             (((size_t)bb * Hc + hh) * HDc + hd) * Tc + t0) = pk;
                }
            } else {
                #pragma unroll
                for (int r = 0; r < 4; r++) {
                    const int row = m0 + wm * 64 + mi * 16 + rq * 4 + r;
                    const size_t idx = (size_t)row * N + col;
                    float vv = acc[mi][ni][r] + bv;
                    if constexpr (EPI == EPI_GELU_BF16) {
                        Cb[idx] = f2b(0.5f * vv * (1.0f + erff(vv * 0.70710678118f)));
                    } else {  // EPI_ATOMIC_F32
                        unsafeAtomicAdd(&Cf[idx], vv);
                    }
                }
            }
        }
}

// ---------------------------------------------------------------- Banded flash attention
// 4-wave K-split per (q-tile, head); NO-MAX softmax (scores bounded; exact —
// softmax is shift-invariant and exp2 clamp at 2^30 can't overflow fp32 sums).
// grid = (bh=48, qt=32): 48%8==0 => all q-tiles of one bh map to one XCD =>
// K/Vt slice (512 KB) stays L2-resident.
// Qb/Kb: [B*T][768]; Vt: [(b*H+h)*64+hd][t]; o: [B*T][768] bf16
__global__ __launch_bounds__(256, 2) void attn_kernel(
    const bf16* __restrict__ Qb, const bf16* __restrict__ Kb,
    const bf16* __restrict__ Vt, bf16* __restrict__ o,
    const int* __restrict__ winp)
{
    const int bh = blockIdx.x, qt = blockIdx.y;
    const int b = bh / Hc, h = bh % Hc;
    const int q0 = qt * 64;
    const int win = *winp;
    const int t = threadIdx.x, wave = t >> 6, lane = t & 63;
    const int rq = lane >> 4, cn = lane & 15;
    constexpr float C1 = 0.125f * 1.44269504089f;   // log2(e)/8

    __shared__ __align__(16) bf16 sQ[64 * 64];
    __shared__ __align__(16) bf16 sP[4][64 * 64];
    __shared__ float sL[4][64], sLf[64];

    const bf16* qp  = Qb + ((size_t)b * Tc + q0) * Dc + h * HDc;
    const bf16* kp  = Kb + ((size_t)b * Tc) * Dc + h * HDc;
    const bf16* vtp = Vt + (size_t)bh * HDc * Tc;

    // stage Q tile [64 rows][64 cols] cooperatively (256 threads, 2x16B each)
    #pragma unroll
    for (int i = 0; i < 2; i++) {
        int c = i * 256 + t;
        int r = c >> 3, c8 = (c & 7) * 8;
        *(uint4*)&sQ[r * 64 + c8] = *(const uint4*)(qp + (size_t)r * Dc + c8);
    }
    __syncthreads();

    float l_i[4][4];
    v4f acc_o[4][4];
    #pragma unroll
    for (int mi = 0; mi < 4; mi++)
        #pragma unroll
        for (int j = 0; j < 4; j++) {
            l_i[mi][j] = 0.0f;
            acc_o[mi][j] = (v4f)(0.0f);
        }

    // key subtiles kb0 = q0 - win + s*64, constrained to [0, Tc-64]
    const int s_lo = (q0 >= win) ? 0 : ((win - q0 + 63) >> 6);
    const int kb_hi = min(Tc - 64, q0 + win);
    const int s_hi = (kb_hi - (q0 - win)) >> 6;          // inclusive

    for (int s = s_lo + wave; s <= s_hi; s += 4) {
        const int kb0 = q0 - win + s * 64;               // in [0, Tc-64]

        // S = Q K^T (64x64); K fragments direct from global (L2-resident)
        v4f sf[4][4];
        #pragma unroll
        for (int mi = 0; mi < 4; mi++)
            #pragma unroll
            for (int ni = 0; ni < 4; ni++) sf[mi][ni] = (v4f)(0.0f);
        #pragma unroll
        for (int ks = 0; ks < 2; ks++) {
            const int kc = ks * 32 + rq * 8;
            v8bf a[4], kf[4];
            #pragma unroll
            for (int mi = 0; mi < 4; mi++)
                a[mi] = *(const v8bf*)&sQ[(mi * 16 + cn) * 64 + kc];
            #pragma unroll
            for (int ni = 0; ni < 4; ni++)
                kf[ni] = *(const v8bf*)(kp + (size_t)(kb0 + ni * 16 + cn) * Dc + kc);
            #pragma unroll
            for (int mi = 0; mi < 4; mi++)
                #pragma unroll
                for (int ni = 0; ni < 4; ni++)
                    sf[mi][ni] = __builtin_amdgcn_mfma_f32_16x16x32_bf16(
                        a[mi], kf[ni], sf[mi][ni], 0, 0, 0);
        }

        // p = exp2(clamp(s * log2e/8)); band mask only on edge subtiles
        const bool need_mask = (q0 + 63 - kb0 > win) || (kb0 + 63 - q0 > win);
        float psum[4][4];
        #pragma unroll
        for (int mi = 0; mi < 4; mi++)
            #pragma unroll
            for (int r = 0; r < 4; r++) psum[mi][r] = 0.0f;
        #pragma unroll
        for (int mi = 0; mi < 4; mi++)
            #pragma unroll
            for (int ni = 0; ni < 4; ni++)
                #pragma unroll
                for (int r = 0; r < 4; r++) {
                    float tt = sf[mi][ni][r] * C1;
                    if (need_mask) {
                        int qi = q0 + mi * 16 + rq * 4 + r;
                        int ki = kb0 + ni * 16 + cn;
                        int dd = qi - ki; dd = dd < 0 ? -dd : dd;
                        tt = (dd > win) ? -INFINITY : tt;
                    }
                    float p = exp2f(fminf(tt, 30.0f));   // masked -> 0
                    psum[mi][r] += p;
                    sP[wave][(mi * 16 + rq * 4 + r) * 64 + ni * 16 + cn] = f2b(p);
                }
        #pragma unroll
        for (int mi = 0; mi < 4; mi++)
            #pragma unroll
            for (int r = 0; r < 4; r++) {
                #pragma unroll
                for (int off = 1; off < 16; off <<= 1)
                    psum[mi][r] += __shfl_xor(psum[mi][r], off, 16);
                l_i[mi][r] += psum[mi][r];
            }

        // O += P V  (A = P [q][k] from sP; B = V^T [hd][k] direct from Vt)
        #pragma unroll
        for (int ks = 0; ks < 2; ks++) {
            const int kc = ks * 32 + rq * 8;
            v8bf pa[4], vf[4];
            #pragma unroll
            for (int mi = 0; mi < 4; mi++)
                pa[mi] = *(const v8bf*)&sP[wave][(mi * 16 + cn) * 64 + kc];
            #pragma unroll
            for (int nh = 0; nh < 4; nh++)
                vf[nh] = *(const v8bf*)(vtp + (size_t)(nh * 16 + cn) * Tc + kb0 + kc);
            #pragma unroll
            for (int mi = 0; mi < 4; mi++)
                #pragma unroll
                for (int nh = 0; nh < 4; nh++)
                    acc_o[mi][nh] = __builtin_amdgcn_mfma_f32_16x16x32_bf16(
                        pa[mi], vf[nh], acc_o[mi][nh], 0, 0, 0);
        }
    }

    // ---- merge: plain sums of per-wave (l, O) ----
    if (cn == 0) {
        #pragma unroll
        for (int mi = 0; mi < 4; mi++)
            #pragma unroll
            for (int r = 0; r < 4; r++)
                sL[wave][mi * 16 + rq * 4 + r] = l_i[mi][r];
    }
    __syncthreads();
    float* oacc = (float*)&sP[0][0];   // 16 KB: overlays sP[0..1] (dead)
    if (t < 64) {
        float Lv = sL[0][t] + sL[1][t] + sL[2][t] + sL[3][t];
        sLf[t] = (Lv > 0.0f) ? 1.0f / Lv : 0.0f;
    }
    #pragma unroll
    for (int w = 0; w < 4; w++) {
        if (wave == w) {
            #pragma unroll
            for (int mi = 0; mi < 4; mi++)
                #pragma unroll
                for (int r = 0; r < 4; r++) {
                    int row = mi * 16 + rq * 4 + r;
                    #pragma unroll
                    for (int nh = 0; nh < 4; nh++) {
                        float* p = &oacc[row * 64 + nh * 16 + cn];
                        if (w == 0) *p = acc_o[mi][nh][r];
                        else        *p += acc_o[mi][nh][r];
                    }
                }
        }
        __syncthreads();
    }
    bf16* ob = o + ((size_t)b * Tc + q0) * Dc + h * HDc;
    for (int i = t; i < 4096; i += 256) {
        int row = i >> 6, col = i & 63;
        ob[(size_t)row * Dc + col] = f2b(oacc[i] * sLf[row]);
    }
}

// ---------------------------------------------------------------- launch
extern "C" void kernel_launch(void* const* d_in, const int* in_sizes, int n_in,
                              void* d_out, int out_size, void* d_ws, size_t ws_size,
                              hipStream_t stream)
{
    const float* x     = (const float*)d_in[0];
    const float* inw   = (const float*)d_in[1];
    const float* inb   = (const float*)d_in[2];
    const float* outw  = (const float*)d_in[3];
    const float* outb  = (const float*)d_in[4];
    const float* w1    = (const float*)d_in[5];
    const float* b1    = (const float*)d_in[6];
    const float* w2    = (const float*)d_in[7];
    const float* b2    = (const float*)d_in[8];
    const float* ln1g  = (const float*)d_in[9];
    const float* ln1b  = (const float*)d_in[10];
    const float* ln2g  = (const float*)d_in[11];
    const float* ln2b  = (const float*)d_in[12];
    const int*   winp  = (const int*)d_in[13];
    float* out = (float*)d_out;   // fp32 [8192][768]; holds x1 mid-pipeline

    // Workspace (55.05 MB needed; >=62.9 MB proven available):
    //   A   [0,      12.58M): xn1 -> obuf -> xn2       (bf16 [8192,768])
    //   QKV [12.58M, 50.33M): Qb | Kb | Vt              (3 x 12.58M bf16)
    //        phase B: hbuf [12.58M, 37.75M) (overlays Qb+Kb, dead)
    //                 w1_b+w2_b [37.75M, 47.19M) (overlays Vt, dead)
    //   WA  [50.33M, 55.05M): wqkv_b + wout_b
    char* ws = (char*)d_ws;
    constexpr size_t A_OFF   = 0;
    constexpr size_t QKV_OFF = (size_t)BTc * Dc * 2;                   // 12582912
    constexpr size_t WA_OFF  = QKV_OFF + 3 * (size_t)BTc * Dc * 2;     // 50331648
    constexpr size_t WS_NEED = WA_OFF + (size_t)(QKVc + Dc) * Dc * 2;  // 55050240
    if (ws_size < WS_NEED) return;

    bf16*  xn     = (bf16*)(ws + A_OFF);            // xn1 / obuf / xn2
    bf16*  qkvb   = (bf16*)(ws + QKV_OFF);          // Qb|Kb|Vt triple
    bf16*  Qb     = qkvb;
    bf16*  Kb     = qkvb + (size_t)BTc * Dc;
    bf16*  Vt     = qkvb + 2 * (size_t)BTc * Dc;
    bf16*  hbuf   = (bf16*)(ws + QKV_OFF);          // phase B
    bf16*  wmlp   = (bf16*)(ws + QKV_OFF + (size_t)BTc * (2 * Dc) * 2);
    bf16*  w1_b   = wmlp;
    bf16*  w2_b   = wmlp + (size_t)MLPc * Dc;
    bf16*  wqkv_b = (bf16*)(ws + WA_OFF);
    bf16*  wout_b = wqkv_b + (size_t)QKVc * Dc;

    constexpr int HALF = MLPc / 2;  // 1536

    // phase-A weight conversion
    cvt_kernel<<<(QKVc * Dc / 4 + 255) / 256, 256, 0, stream>>>(inw, wqkv_b, QKVc * Dc / 4);
    cvt_kernel<<<(Dc * Dc / 4 + 255) / 256, 256, 0, stream>>>(outw, wout_b, Dc * Dc / 4);

    // 1. LN1 (fp32 x -> bf16 xn)
    ln_kernel<<<BTc, 256, 0, stream>>>(x, ln1g, ln1b, xn);
    // 2. qkv GEMM with split-store epilogue -> Qb | Kb | Vt(transposed)
    gemm_bt<EPI_QKV><<<dim3(QKVc / 128, BTc / 128), 256, 0, stream>>>(
        xn, wqkv_b, inb, qkvb, nullptr, BTc, QKVc, Dc, Dc, Dc);
    // 3. banded attention (4-wave K-split, XCD-local grid) -> obuf (= xn)
    attn_kernel<<<dim3(Bc * Hc, Tc / 64), 256, 0, stream>>>(Qb, Kb, Vt, xn, winp);
    // 4. out(x1) = x + obuf @ out_w^T + out_b   (split-K=2, fp32 atomics)
    hipMemcpyAsync(out, x, (size_t)BTc * Dc * sizeof(float),
                   hipMemcpyDeviceToDevice, stream);
    gemm_bt<EPI_ATOMIC_F32><<<dim3(Dc / 128, BTc / 128, 2), 256, 0, stream>>>(
        xn, wout_b, outb, nullptr, out, BTc, Dc, Dc / 2, Dc, Dc);
    // 5. LN2 (d_out fp32 -> bf16 xn2)
    ln_kernel<<<BTc, 256, 0, stream>>>(out, ln2g, ln2b, xn);
    // phase-B weight conversion (overlays dead Vt region)
    cvt_kernel<<<(MLPc * Dc / 4 + 255) / 256, 256, 0, stream>>>(w1, w1_b, MLPc * Dc / 4);
    cvt_kernel<<<(Dc * MLPc / 4 + 255) / 256, 256, 0, stream>>>(w2, w2_b, Dc * MLPc / 4);

    // 6/7. MLP in two 1536-wide halves; d_out holds x1, accumulate onto it
    for (int c = 0; c < 2; c++) {
        const bf16* w1c = w1_b + (size_t)c * HALF * Dc;   // rows [c*1536, ..)
        const bf16* w2c = w2_b + (size_t)c * HALF;        // cols [c*1536, ..)
        gemm_bt<EPI_GELU_BF16><<<dim3(HALF / 128, BTc / 128), 256, 0, stream>>>(
            xn, w1c, b1 + c * HALF, hbuf, nullptr, BTc, HALF, Dc, Dc, Dc);
        // down-proj: split-K=2 over this half's K=1536
        gemm_bt<EPI_ATOMIC_F32><<<dim3(Dc / 128, BTc / 128, 2), 256, 0, stream>>>(
            hbuf, w2c, (c == 0) ? b2 : nullptr, nullptr, out,
            BTc, Dc, HALF / 2, HALF, MLPc);
    }
}

// Round 7
// 428.124 us; speedup vs baseline: 1.3464x; 1.3464x over previous
//
#include <hip/hip_runtime.h>
#include <hip/hip_bf16.h>

typedef __bf16 bf16;
typedef __bf16 v8bf __attribute__((ext_vector_type(8)));
typedef __bf16 v4bf __attribute__((ext_vector_type(4)));
typedef float  v4f  __attribute__((ext_vector_type(4)));

#define DEVI __device__ __forceinline__

constexpr int Bc   = 4;
constexpr int Tc   = 2048;
constexpr int Dc   = 768;
constexpr int Hc   = 12;
constexpr int HDc  = 64;
constexpr int MLPc = 3072;
constexpr int QKVc = 2304;    // 3*D
constexpr int BTc  = Bc * Tc; // 8192 rows

DEVI float b2f(bf16 x) { return (float)x; }
DEVI bf16  f2b(float x) { return (bf16)x; }

// async global->LDS, 16B per lane; lds dest = wave-uniform base + lane*16
#define GLDS(gp, lp) __builtin_amdgcn_global_load_lds( \
    (const __attribute__((address_space(1))) void*)(gp), \
    (__attribute__((address_space(3))) void*)(lp), 16, 0, 0)

// ---------------------------------------------------------------- fp32 -> bf16 weight conversion
__global__ __launch_bounds__(256) void cvt_kernel(
    const float* __restrict__ s, bf16* __restrict__ d, int n4)
{
    int i = blockIdx.x * 256 + threadIdx.x;
    if (i < n4) {
        float4 v = ((const float4*)s)[i];
        v4bf o = { f2b(v.x), f2b(v.y), f2b(v.z), f2b(v.w) };
        ((v4bf*)d)[i] = o;
    }
}

// ---------------------------------------------------------------- LayerNorm (fp32 in, bf16 out)
__global__ __launch_bounds__(256) void ln_kernel(
    const float* __restrict__ x, const float* __restrict__ g,
    const float* __restrict__ bt, bf16* __restrict__ out)
{
    const int row = blockIdx.x;
    const int t = threadIdx.x;
    const float* xr = x + (size_t)row * Dc;
    float v[3];
    v[0] = xr[t];
    v[1] = xr[t + 256];
    v[2] = xr[t + 512];
    float s = v[0] + v[1] + v[2];
    float s2 = v[0]*v[0] + v[1]*v[1] + v[2]*v[2];
    #pragma unroll
    for (int off = 32; off > 0; off >>= 1) {
        s  += __shfl_down(s, off);
        s2 += __shfl_down(s2, off);
    }
    __shared__ float red[8];
    const int wave = t >> 6, lane = t & 63;
    if (lane == 0) { red[wave] = s; red[4 + wave] = s2; }
    __syncthreads();
    s  = red[0] + red[1] + red[2] + red[3];
    s2 = red[4] + red[5] + red[6] + red[7];
    const float mean = s * (1.0f / Dc);
    const float var  = s2 * (1.0f / Dc) - mean * mean;
    const float rstd = rsqrtf(var + 1e-5f);
    bf16* orow = out + (size_t)row * Dc;
    #pragma unroll
    for (int i = 0; i < 3; i++) {
        int c = t + i * 256;
        orow[c] = f2b((v[i] - mean) * rstd * g[c] + bt[c]);
    }
}

// ---------------------------------------------------------------- GEMM (C = A @ B^T + bias, fused epilogues)
// A: [M][lda] bf16 row-major; Bw: [N rows][ldb] bf16, K columns used.
// XCD stripe swizzle: XCD (bid&7) owns M-rows [xcd*M/8, ...) so its A-stripe
// + B stay L2-resident. LDS XOR swizzle kills 16-way ds_read_b128 conflicts.
// EPI_QKV: Cb = base of Qb|Kb|Vt triple; Q/K stored [8192][768], V stored
//          transposed Vt[(b*H+h)*64+hd][t].
enum { EPI_QKV = 0, EPI_GELU_BF16 = 1, EPI_RESID_F32 = 2, EPI_ACC_F32 = 3 };

template <int EPI>
__global__ __launch_bounds__(256) void gemm_bt(
    const bf16* __restrict__ A, const bf16* __restrict__ Bw,
    const float* __restrict__ bias,
    bf16* __restrict__ Cb, float* __restrict__ Cf,
    const float* __restrict__ resf,
    int M, int N, int K, int lda, int ldb)
{
    __shared__ __align__(16) bf16 sA[128 * 64];
    __shared__ __align__(16) bf16 sB[128 * 64];
    const int t = threadIdx.x, wave = t >> 6, lane = t & 63;
    const int wm = wave & 1, wn = wave >> 1;
    // XCD stripe swizzle (ny divisible by 8 for all our shapes)
    const int nx = gridDim.x, ny = gridDim.y;
    const int bid = blockIdx.y * nx + blockIdx.x;
    const int xcd = bid & 7, kk = bid >> 3;
    const int m0 = (xcd * (ny >> 3) + kk / nx) * 128;
    const int n0 = (kk % nx) * 128;
    const bf16* Ag = A + (size_t)m0 * lda;
    const bf16* Bg = Bw + (size_t)n0 * ldb;

    v4f acc[4][4];
    #pragma unroll
    for (int i = 0; i < 4; i++)
        #pragma unroll
        for (int j = 0; j < 4; j++) acc[i][j] = (v4f)(0.0f);

    for (int k0 = 0; k0 < K; k0 += 64) {
        // stage with XOR swizzle: LDS slot c holds global chunk (c&7)^(r&7)
        // of row r=c>>3 (GLDS dest is lane-fixed; source carries permutation,
        // staying within the row's 128B segment => coalescing intact)
        #pragma unroll
        for (int i = 0; i < 4; i++) {
            int c = i * 256 + t;
            int r = c >> 3, j = (c & 7) ^ (r & 7);
            GLDS(Ag + (size_t)r * lda + k0 + j * 8,
                 &sA[(i * 256 + wave * 64) * 8]);
        }
        #pragma unroll
        for (int i = 0; i < 4; i++) {
            int c = i * 256 + t;
            int r = c >> 3, j = (c & 7) ^ (r & 7);
            GLDS(Bg + (size_t)r * ldb + k0 + j * 8,
                 &sB[(i * 256 + wave * 64) * 8]);
        }
        __syncthreads();
        #pragma unroll
        for (int ks = 0; ks < 2; ks++) {
            const int rq = lane >> 4, rl = lane & 15;
            v8bf a[4], b[4];
            #pragma unroll
            for (int mi = 0; mi < 4; mi++) {
                const int row = wm * 64 + mi * 16 + rl;
                a[mi] = *(const v8bf*)&sA[row * 64 + ((ks * 4 + rq) ^ (row & 7)) * 8];
            }
            #pragma unroll
            for (int ni = 0; ni < 4; ni++) {
                const int row = wn * 64 + ni * 16 + rl;
                b[ni] = *(const v8bf*)&sB[row * 64 + ((ks * 4 + rq) ^ (row & 7)) * 8];
            }
            #pragma unroll
            for (int mi = 0; mi < 4; mi++)
                #pragma unroll
                for (int ni = 0; ni < 4; ni++)
                    acc[mi][ni] = __builtin_amdgcn_mfma_f32_16x16x32_bf16(
                        a[mi], b[ni], acc[mi][ni], 0, 0, 0);
        }
        __syncthreads();
    }

    const int rq = lane >> 4, cn = lane & 15;
    #pragma unroll
    for (int mi = 0; mi < 4; mi++)
        #pragma unroll
        for (int ni = 0; ni < 4; ni++) {
            const int col = n0 + wn * 64 + ni * 16 + cn;
            const float bv = bias ? bias[col] : 0.0f;
            if constexpr (EPI == EPI_QKV) {
                const int row0 = m0 + wm * 64 + mi * 16 + rq * 4;
                if (n0 < 2 * Dc) {
                    bf16* dst = Cb + (col < Dc ? 0 : (size_t)BTc * Dc);
                    const int cadj = col < Dc ? col : col - Dc;
                    #pragma unroll
                    for (int r = 0; r < 4; r++)
                        dst[(size_t)(row0 + r) * Dc + cadj] = f2b(acc[mi][ni][r] + bv);
                } else {
                    const int vcol = col - 2 * Dc;
                    const int hh = vcol >> 6, hd = vcol & 63;
                    const int bb = row0 >> 11, t0 = row0 & 2047;
                    v4bf pk;
                    #pragma unroll
                    for (int r = 0; r < 4; r++) pk[r] = f2b(acc[mi][ni][r] + bv);
                    *(v4bf*)(Cb + 2 * (size_t)BTc * Dc +
                             (((size_t)bb * Hc + hh) * HDc + hd) * Tc + t0) = pk;
                }
            } else {
                #pragma unroll
                for (int r = 0; r < 4; r++) {
                    const int row = m0 + wm * 64 + mi * 16 + rq * 4 + r;
                    const size_t idx = (size_t)row * N + col;
                    float vv = acc[mi][ni][r] + bv;
                    if constexpr (EPI == EPI_GELU_BF16) {
                        Cb[idx] = f2b(0.5f * vv * (1.0f + erff(vv * 0.70710678118f)));
                    } else if constexpr (EPI == EPI_RESID_F32) {
                        Cf[idx] = vv + resf[idx];
                    } else {  // EPI_ACC_F32: sequential RMW accumulate
                        Cf[idx] = vv + Cf[idx];
                    }
                }
            }
        }
}

// ---------------------------------------------------------------- Banded flash attention
// 4-wave K-split per (q-tile, head); no-max softmax (exact: shift-invariant,
// scores bounded so exp2 clamp at 2^30 can't overflow fp32 sums).
// grid = (bh=48, qt=32): 48%8==0 => all q-tiles of one bh on one XCD =>
// K/Vt slice stays L2-resident.
__global__ __launch_bounds__(256, 2) void attn_kernel(
    const bf16* __restrict__ Qb, const bf16* __restrict__ Kb,
    const bf16* __restrict__ Vt, bf16* __restrict__ o,
    const int* __restrict__ winp)
{
    const int bh = blockIdx.x, qt = blockIdx.y;
    const int b = bh / Hc, h = bh % Hc;
    const int q0 = qt * 64;
    const int win = *winp;
    const int t = threadIdx.x, wave = t >> 6, lane = t & 63;
    const int rq = lane >> 4, cn = lane & 15;
    constexpr float C1 = 0.125f * 1.44269504089f;   // log2(e)/8

    __shared__ __align__(16) bf16 sQ[64 * 64];
    __shared__ __align__(16) bf16 sP[4][64 * 64];
    __shared__ float sL[4][64], sLf[64];

    const bf16* qp  = Qb + ((size_t)b * Tc + q0) * Dc + h * HDc;
    const bf16* kp  = Kb + ((size_t)b * Tc) * Dc + h * HDc;
    const bf16* vtp = Vt + (size_t)bh * HDc * Tc;

    // stage Q tile [64 rows][64 cols] cooperatively (256 threads, 2x16B each)
    #pragma unroll
    for (int i = 0; i < 2; i++) {
        int c = i * 256 + t;
        int r = c >> 3, c8 = (c & 7) * 8;
        *(uint4*)&sQ[r * 64 + c8] = *(const uint4*)(qp + (size_t)r * Dc + c8);
    }
    __syncthreads();

    float l_i[4][4];
    v4f acc_o[4][4];
    #pragma unroll
    for (int mi = 0; mi < 4; mi++)
        #pragma unroll
        for (int j = 0; j < 4; j++) {
            l_i[mi][j] = 0.0f;
            acc_o[mi][j] = (v4f)(0.0f);
        }

    // key subtiles kb0 = q0 - win + s*64, constrained to [0, Tc-64]
    const int s_lo = (q0 >= win) ? 0 : ((win - q0 + 63) >> 6);
    const int kb_hi = min(Tc - 64, q0 + win);
    const int s_hi = (kb_hi - (q0 - win)) >> 6;          // inclusive

    for (int s = s_lo + wave; s <= s_hi; s += 4) {
        const int kb0 = q0 - win + s * 64;               // in [0, Tc-64]

        // S = Q K^T (64x64); K fragments direct from global (L2-resident)
        v4f sf[4][4];
        #pragma unroll
        for (int mi = 0; mi < 4; mi++)
            #pragma unroll
            for (int ni = 0; ni < 4; ni++) sf[mi][ni] = (v4f)(0.0f);
        #pragma unroll
        for (int ks = 0; ks < 2; ks++) {
            const int kc = ks * 32 + rq * 8;
            v8bf a[4], kf[4];
            #pragma unroll
            for (int mi = 0; mi < 4; mi++)
                a[mi] = *(const v8bf*)&sQ[(mi * 16 + cn) * 64 + kc];
            #pragma unroll
            for (int ni = 0; ni < 4; ni++)
                kf[ni] = *(const v8bf*)(kp + (size_t)(kb0 + ni * 16 + cn) * Dc + kc);
            #pragma unroll
            for (int mi = 0; mi < 4; mi++)
                #pragma unroll
                for (int ni = 0; ni < 4; ni++)
                    sf[mi][ni] = __builtin_amdgcn_mfma_f32_16x16x32_bf16(
                        a[mi], kf[ni], sf[mi][ni], 0, 0, 0);
        }

        // p = exp2(clamp(s * log2e/8)); band mask only on edge subtiles
        const bool need_mask = (q0 + 63 - kb0 > win) || (kb0 + 63 - q0 > win);
        float psum[4][4];
        #pragma unroll
        for (int mi = 0; mi < 4; mi++)
            #pragma unroll
            for (int r = 0; r < 4; r++) psum[mi][r] = 0.0f;
        #pragma unroll
        for (int mi = 0; mi < 4; mi++)
            #pragma unroll
            for (int ni = 0; ni < 4; ni++)
                #pragma unroll
                for (int r = 0; r < 4; r++) {
                    float tt = sf[mi][ni][r] * C1;
                    if (need_mask) {
                        int qi = q0 + mi * 16 + rq * 4 + r;
                        int ki = kb0 + ni * 16 + cn;
                        int dd = qi - ki; dd = dd < 0 ? -dd : dd;
                        tt = (dd > win) ? -INFINITY : tt;
                    }
                    float p = exp2f(fminf(tt, 30.0f));   // masked -> 0
                    psum[mi][r] += p;
                    sP[wave][(mi * 16 + rq * 4 + r) * 64 + ni * 16 + cn] = f2b(p);
                }
        #pragma unroll
        for (int mi = 0; mi < 4; mi++)
            #pragma unroll
            for (int r = 0; r < 4; r++) {
                #pragma unroll
                for (int off = 1; off < 16; off <<= 1)
                    psum[mi][r] += __shfl_xor(psum[mi][r], off, 16);
                l_i[mi][r] += psum[mi][r];
            }

        // O += P V  (A = P [q][k] from sP; B = V^T [hd][k] direct from Vt)
        #pragma unroll
        for (int ks = 0; ks < 2; ks++) {
            const int kc = ks * 32 + rq * 8;
            v8bf pa[4], vf[4];
            #pragma unroll
            for (int mi = 0; mi < 4; mi++)
                pa[mi] = *(const v8bf*)&sP[wave][(mi * 16 + cn) * 64 + kc];
            #pragma unroll
            for (int nh = 0; nh < 4; nh++)
                vf[nh] = *(const v8bf*)(vtp + (size_t)(nh * 16 + cn) * Tc + kb0 + kc);
            #pragma unroll
            for (int mi = 0; mi < 4; mi++)
                #pragma unroll
                for (int nh = 0; nh < 4; nh++)
                    acc_o[mi][nh] = __builtin_amdgcn_mfma_f32_16x16x32_bf16(
                        pa[mi], vf[nh], acc_o[mi][nh], 0, 0, 0);
        }
    }

    // ---- merge: plain sums of per-wave (l, O) ----
    if (cn == 0) {
        #pragma unroll
        for (int mi = 0; mi < 4; mi++)
            #pragma unroll
            for (int r = 0; r < 4; r++)
                sL[wave][mi * 16 + rq * 4 + r] = l_i[mi][r];
    }
    __syncthreads();
    float* oacc = (float*)&sP[0][0];   // 16 KB: overlays sP[0..1] (dead)
    if (t < 64) {
        float Lv = sL[0][t] + sL[1][t] + sL[2][t] + sL[3][t];
        sLf[t] = (Lv > 0.0f) ? 1.0f / Lv : 0.0f;
    }
    #pragma unroll
    for (int w = 0; w < 4; w++) {
        if (wave == w) {
            #pragma unroll
            for (int mi = 0; mi < 4; mi++)
                #pragma unroll
                for (int r = 0; r < 4; r++) {
                    int row = mi * 16 + rq * 4 + r;
                    #pragma unroll
                    for (int nh = 0; nh < 4; nh++) {
                        float* p = &oacc[row * 64 + nh * 16 + cn];
                        if (w == 0) *p = acc_o[mi][nh][r];
                        else        *p += acc_o[mi][nh][r];
                    }
                }
        }
        __syncthreads();
    }
    bf16* ob = o + ((size_t)b * Tc + q0) * Dc + h * HDc;
    for (int i = t; i < 4096; i += 256) {
        int row = i >> 6, col = i & 63;
        ob[(size_t)row * Dc + col] = f2b(oacc[i] * sLf[row]);
    }
}

// ---------------------------------------------------------------- launch
extern "C" void kernel_launch(void* const* d_in, const int* in_sizes, int n_in,
                              void* d_out, int out_size, void* d_ws, size_t ws_size,
                              hipStream_t stream)
{
    const float* x     = (const float*)d_in[0];
    const float* inw   = (const float*)d_in[1];
    const float* inb   = (const float*)d_in[2];
    const float* outw  = (const float*)d_in[3];
    const float* outb  = (const float*)d_in[4];
    const float* w1    = (const float*)d_in[5];
    const float* b1    = (const float*)d_in[6];
    const float* w2    = (const float*)d_in[7];
    const float* b2    = (const float*)d_in[8];
    const float* ln1g  = (const float*)d_in[9];
    const float* ln1b  = (const float*)d_in[10];
    const float* ln2g  = (const float*)d_in[11];
    const float* ln2b  = (const float*)d_in[12];
    const int*   winp  = (const int*)d_in[13];
    float* out = (float*)d_out;   // fp32 [8192][768]; holds x1 mid-pipeline

    // Workspace (55.05 MB needed; >=62.9 MB proven available):
    //   A   [0,      12.58M): xn1 -> obuf -> xn2       (bf16 [8192,768])
    //   QKV [12.58M, 50.33M): Qb | Kb | Vt              (3 x 12.58M bf16)
    //        phase B: hbuf [12.58M, 37.75M) (overlays Qb+Kb, dead)
    //                 w1_b+w2_b [37.75M, 47.19M) (overlays Vt, dead)
    //   WA  [50.33M, 55.05M): wqkv_b + wout_b
    char* ws = (char*)d_ws;
    constexpr size_t A_OFF   = 0;
    constexpr size_t QKV_OFF = (size_t)BTc * Dc * 2;                   // 12582912
    constexpr size_t WA_OFF  = QKV_OFF + 3 * (size_t)BTc * Dc * 2;     // 50331648
    constexpr size_t WS_NEED = WA_OFF + (size_t)(QKVc + Dc) * Dc * 2;  // 55050240
    if (ws_size < WS_NEED) return;

    bf16*  xn     = (bf16*)(ws + A_OFF);            // xn1 / obuf / xn2
    bf16*  qkvb   = (bf16*)(ws + QKV_OFF);          // Qb|Kb|Vt triple
    bf16*  Qb     = qkvb;
    bf16*  Kb     = qkvb + (size_t)BTc * Dc;
    bf16*  Vt     = qkvb + 2 * (size_t)BTc * Dc;
    bf16*  hbuf   = (bf16*)(ws + QKV_OFF);          // phase B
    bf16*  wmlp   = (bf16*)(ws + QKV_OFF + (size_t)BTc * (2 * Dc) * 2);
    bf16*  w1_b   = wmlp;
    bf16*  w2_b   = wmlp + (size_t)MLPc * Dc;
    bf16*  wqkv_b = (bf16*)(ws + WA_OFF);
    bf16*  wout_b = wqkv_b + (size_t)QKVc * Dc;

    constexpr int HALF = MLPc / 2;  // 1536

    // phase-A weight conversion
    cvt_kernel<<<(QKVc * Dc / 4 + 255) / 256, 256, 0, stream>>>(inw, wqkv_b, QKVc * Dc / 4);
    cvt_kernel<<<(Dc * Dc / 4 + 255) / 256, 256, 0, stream>>>(outw, wout_b, Dc * Dc / 4);

    // 1. LN1 (fp32 x -> bf16 xn)
    ln_kernel<<<BTc, 256, 0, stream>>>(x, ln1g, ln1b, xn);
    // 2. qkv GEMM with split-store epilogue -> Qb | Kb | Vt(transposed)
    gemm_bt<EPI_QKV><<<dim3(QKVc / 128, BTc / 128), 256, 0, stream>>>(
        xn, wqkv_b, inb, qkvb, nullptr, nullptr, BTc, QKVc, Dc, Dc, Dc);
    // 3. banded attention (4-wave K-split, XCD-local grid) -> obuf (= xn)
    attn_kernel<<<dim3(Bc * Hc, Tc / 64), 256, 0, stream>>>(Qb, Kb, Vt, xn, winp);
    // 4. out(x1) = x + obuf @ out_w^T + out_b   (fp32, fused residual)
    gemm_bt<EPI_RESID_F32><<<dim3(Dc / 128, BTc / 128), 256, 0, stream>>>(
        xn, wout_b, outb, nullptr, out, x, BTc, Dc, Dc, Dc, Dc);
    // 5. LN2 (d_out fp32 -> bf16 xn2)
    ln_kernel<<<BTc, 256, 0, stream>>>(out, ln2g, ln2b, xn);
    // phase-B weight conversion (overlays dead Vt region)
    cvt_kernel<<<(MLPc * Dc / 4 + 255) / 256, 256, 0, stream>>>(w1, w1_b, MLPc * Dc / 4);
    cvt_kernel<<<(Dc * MLPc / 4 + 255) / 256, 256, 0, stream>>>(w2, w2_b, Dc * MLPc / 4);

    // 6/7. MLP in two 1536-wide halves; d_out holds x1, accumulate onto it
    for (int c = 0; c < 2; c++) {
        const bf16* w1c = w1_b + (size_t)c * HALF * Dc;   // rows [c*1536, ..)
        const bf16* w2c = w2_b + (size_t)c * HALF;        // cols [c*1536, ..)
        gemm_bt<EPI_GELU_BF16><<<dim3(HALF / 128, BTc / 128), 256, 0, stream>>>(
            xn, w1c, b1 + c * HALF, hbuf, nullptr, nullptr, BTc, HALF, Dc, Dc, Dc);
        // down-proj: A = hbuf [8192][HALF] => lda = HALF (R6 bug: was MLPc)
        gemm_bt<EPI_ACC_F32><<<dim3(Dc / 128, BTc / 128), 256, 0, stream>>>(
            hbuf, w2c, (c == 0) ? b2 : nullptr, nullptr, out, nullptr,
            BTc, Dc, HALF, HALF, MLPc);
    }
}

// Round 8
// 383.351 us; speedup vs baseline: 1.5037x; 1.1168x over previous
//
#include <hip/hip_runtime.h>
#include <hip/hip_bf16.h>

typedef __bf16 bf16;
typedef __bf16 v8bf __attribute__((ext_vector_type(8)));
typedef __bf16 v4bf __attribute__((ext_vector_type(4)));
typedef float  v4f  __attribute__((ext_vector_type(4)));

#define DEVI __device__ __forceinline__

constexpr int Bc   = 4;
constexpr int Tc   = 2048;
constexpr int Dc   = 768;
constexpr int Hc   = 12;
constexpr int HDc  = 64;
constexpr int MLPc = 3072;
constexpr int QKVc = 2304;    // 3*D
constexpr int BTc  = Bc * Tc; // 8192 rows
constexpr int SPAD = 72;      // LDS row stride (元素): 144B = 36 banks, kills 8/16-way conflicts

DEVI float b2f(bf16 x) { return (float)x; }
DEVI bf16  f2b(float x) { return (bf16)x; }

// async global->LDS, 16B per lane; lds dest = wave-uniform base + lane*16
#define GLDS(gp, lp) __builtin_amdgcn_global_load_lds( \
    (const __attribute__((address_space(1))) void*)(gp), \
    (__attribute__((address_space(3))) void*)(lp), 16, 0, 0)

// ---------------------------------------------------------------- fp32 -> bf16 weight conversion
__global__ __launch_bounds__(256) void cvt_kernel(
    const float* __restrict__ s, bf16* __restrict__ d, int n4)
{
    int i = blockIdx.x * 256 + threadIdx.x;
    if (i < n4) {
        float4 v = ((const float4*)s)[i];
        v4bf o = { f2b(v.x), f2b(v.y), f2b(v.z), f2b(v.w) };
        ((v4bf*)d)[i] = o;
    }
}

// ---------------------------------------------------------------- LayerNorm (fp32 in, bf16 out)
__global__ __launch_bounds__(256) void ln_kernel(
    const float* __restrict__ x, const float* __restrict__ g,
    const float* __restrict__ bt, bf16* __restrict__ out)
{
    const int row = blockIdx.x;
    const int t = threadIdx.x;
    const float* xr = x + (size_t)row * Dc;
    float v[3];
    v[0] = xr[t];
    v[1] = xr[t + 256];
    v[2] = xr[t + 512];
    float s = v[0] + v[1] + v[2];
    float s2 = v[0]*v[0] + v[1]*v[1] + v[2]*v[2];
    #pragma unroll
    for (int off = 32; off > 0; off >>= 1) {
        s  += __shfl_down(s, off);
        s2 += __shfl_down(s2, off);
    }
    __shared__ float red[8];
    const int wave = t >> 6, lane = t & 63;
    if (lane == 0) { red[wave] = s; red[4 + wave] = s2; }
    __syncthreads();
    s  = red[0] + red[1] + red[2] + red[3];
    s2 = red[4] + red[5] + red[6] + red[7];
    const float mean = s * (1.0f / Dc);
    const float var  = s2 * (1.0f / Dc) - mean * mean;
    const float rstd = rsqrtf(var + 1e-5f);
    bf16* orow = out + (size_t)row * Dc;
    #pragma unroll
    for (int i = 0; i < 3; i++) {
        int c = t + i * 256;
        orow[c] = f2b((v[i] - mean) * rstd * g[c] + bt[c]);
    }
}

// ---------------------------------------------------------------- GEMM (C = A @ B^T + bias, fused epilogues)
// A: [M][lda] bf16 row-major; Bw: [N rows][ldb] bf16, K columns used.
// TN = 128 (4 waves of 64x64) or 64 (4 waves of 32x64; doubles grid for
// small-N GEMMs -> occupancy). XCD stripe swizzle + XOR LDS swizzle.
// EPI_QKV (TN=128 only): Cb = Qb|Kb|Vt triple; V stored transposed.
enum { EPI_QKV = 0, EPI_GELU_BF16 = 1, EPI_RESID_F32 = 2, EPI_ACC_F32 = 3 };

template <int EPI, int TN>
__global__ __launch_bounds__(256) void gemm_bt(
    const bf16* __restrict__ A, const bf16* __restrict__ Bw,
    const float* __restrict__ bias,
    bf16* __restrict__ Cb, float* __restrict__ Cf,
    const float* __restrict__ resf,
    int M, int N, int K, int lda, int ldb)
{
    constexpr int MI = (TN == 128) ? 4 : 2;      // 16-row blocks per wave (m)
    __shared__ __align__(16) bf16 sA[128 * 64];
    __shared__ __align__(16) bf16 sB[TN * 64];
    const int t = threadIdx.x, wave = t >> 6, lane = t & 63;
    const int moff = (TN == 128) ? (wave & 1) * 64 : wave * 32;
    const int noff = (TN == 128) ? (wave >> 1) * 64 : 0;
    // XCD stripe swizzle (ny divisible by 8 for all our shapes)
    const int nx = gridDim.x, ny = gridDim.y;
    const int bid = blockIdx.y * nx + blockIdx.x;
    const int xcd = bid & 7, kk = bid >> 3;
    const int m0 = (xcd * (ny >> 3) + kk / nx) * 128;
    const int n0 = (kk % nx) * TN;
    const bf16* Ag = A + (size_t)m0 * lda;
    const bf16* Bg = Bw + (size_t)n0 * ldb;

    v4f acc[MI][4];
    #pragma unroll
    for (int i = 0; i < MI; i++)
        #pragma unroll
        for (int j = 0; j < 4; j++) acc[i][j] = (v4f)(0.0f);

    for (int k0 = 0; k0 < K; k0 += 64) {
        // stage with XOR swizzle: LDS slot c holds global chunk (c&7)^(r&7)
        // of row r=c>>3 (source carries permutation within the row's 128B)
        #pragma unroll
        for (int i = 0; i < 4; i++) {
            int c = i * 256 + t;
            int r = c >> 3, j = (c & 7) ^ (r & 7);
            GLDS(Ag + (size_t)r * lda + k0 + j * 8,
                 &sA[(i * 256 + wave * 64) * 8]);
        }
        #pragma unroll
        for (int i = 0; i < TN / 32; i++) {
            int c = i * 256 + t;
            int r = c >> 3, j = (c & 7) ^ (r & 7);
            GLDS(Bg + (size_t)r * ldb + k0 + j * 8,
                 &sB[(i * 256 + wave * 64) * 8]);
        }
        __syncthreads();
        #pragma unroll
        for (int ks = 0; ks < 2; ks++) {
            const int rq = lane >> 4, rl = lane & 15;
            v8bf a[MI], b[4];
            #pragma unroll
            for (int mi = 0; mi < MI; mi++) {
                const int row = moff + mi * 16 + rl;
                a[mi] = *(const v8bf*)&sA[row * 64 + ((ks * 4 + rq) ^ (row & 7)) * 8];
            }
            #pragma unroll
            for (int ni = 0; ni < 4; ni++) {
                const int row = noff + ni * 16 + rl;
                b[ni] = *(const v8bf*)&sB[row * 64 + ((ks * 4 + rq) ^ (row & 7)) * 8];
            }
            #pragma unroll
            for (int mi = 0; mi < MI; mi++)
                #pragma unroll
                for (int ni = 0; ni < 4; ni++)
                    acc[mi][ni] = __builtin_amdgcn_mfma_f32_16x16x32_bf16(
                        a[mi], b[ni], acc[mi][ni], 0, 0, 0);
        }
        __syncthreads();
    }

    const int rq = lane >> 4, cn = lane & 15;
    #pragma unroll
    for (int mi = 0; mi < MI; mi++)
        #pragma unroll
        for (int ni = 0; ni < 4; ni++) {
            const int col = n0 + noff + ni * 16 + cn;
            const float bv = bias ? bias[col] : 0.0f;
            if constexpr (EPI == EPI_QKV) {
                const int row0 = m0 + moff + mi * 16 + rq * 4;
                if (n0 < 2 * Dc) {
                    bf16* dst = Cb + (col < Dc ? 0 : (size_t)BTc * Dc);
                    const int cadj = col < Dc ? col : col - Dc;
                    #pragma unroll
                    for (int r = 0; r < 4; r++)
                        dst[(size_t)(row0 + r) * Dc + cadj] = f2b(acc[mi][ni][r] + bv);
                } else {
                    const int vcol = col - 2 * Dc;
                    const int hh = vcol >> 6, hd = vcol & 63;
                    const int bb = row0 >> 11, t0 = row0 & 2047;
                    v4bf pk;
                    #pragma unroll
                    for (int r = 0; r < 4; r++) pk[r] = f2b(acc[mi][ni][r] + bv);
                    *(v4bf*)(Cb + 2 * (size_t)BTc * Dc +
                             (((size_t)bb * Hc + hh) * HDc + hd) * Tc + t0) = pk;
                }
            } else {
                #pragma unroll
                for (int r = 0; r < 4; r++) {
                    const int row = m0 + moff + mi * 16 + rq * 4 + r;
                    const size_t idx = (size_t)row * N + col;
                    float vv = acc[mi][ni][r] + bv;
                    if constexpr (EPI == EPI_GELU_BF16) {
                        Cb[idx] = f2b(0.5f * vv * (1.0f + erff(vv * 0.70710678118f)));
                    } else if constexpr (EPI == EPI_RESID_F32) {
                        Cf[idx] = vv + resf[idx];
                    } else {  // EPI_ACC_F32: sequential RMW accumulate
                        Cf[idx] = vv + Cf[idx];
                    }
                }
            }
        }
}

// ---------------------------------------------------------------- Banded flash attention
// 4-wave K-split per (q-tile, head); no-max softmax (exact: shift-invariant,
// scores bounded so exp2 clamp at 2^30 can't overflow fp32 sums).
// grid = (bh=48, qt=32): 48%8==0 => all q-tiles of one bh on one XCD.
// LDS rows padded to SPAD=72 el: P-writes 8-way->4-way, b128 reads 16-way->free.
__global__ __launch_bounds__(256, 2) void attn_kernel(
    const bf16* __restrict__ Qb, const bf16* __restrict__ Kb,
    const bf16* __restrict__ Vt, bf16* __restrict__ o,
    const int* __restrict__ winp)
{
    const int bh = blockIdx.x, qt = blockIdx.y;
    const int b = bh / Hc, h = bh % Hc;
    const int q0 = qt * 64;
    const int win = *winp;
    const int t = threadIdx.x, wave = t >> 6, lane = t & 63;
    const int rq = lane >> 4, cn = lane & 15;
    constexpr float C1 = 0.125f * 1.44269504089f;   // log2(e)/8

    __shared__ __align__(16) bf16 sQ[64 * SPAD];
    __shared__ __align__(16) bf16 sP[4][64 * SPAD];
    __shared__ float sL[4][64], sLf[64];

    const bf16* qp  = Qb + ((size_t)b * Tc + q0) * Dc + h * HDc;
    const bf16* kp  = Kb + ((size_t)b * Tc) * Dc + h * HDc;
    const bf16* vtp = Vt + (size_t)bh * HDc * Tc;

    // stage Q tile [64 rows][64 cols] cooperatively (256 threads, 2x16B each)
    #pragma unroll
    for (int i = 0; i < 2; i++) {
        int c = i * 256 + t;
        int r = c >> 3, c8 = (c & 7) * 8;
        *(uint4*)&sQ[r * SPAD + c8] = *(const uint4*)(qp + (size_t)r * Dc + c8);
    }
    __syncthreads();

    float l_i[4][4];
    v4f acc_o[4][4];
    #pragma unroll
    for (int mi = 0; mi < 4; mi++)
        #pragma unroll
        for (int j = 0; j < 4; j++) {
            l_i[mi][j] = 0.0f;
            acc_o[mi][j] = (v4f)(0.0f);
        }

    // key subtiles kb0 = q0 - win + s*64, constrained to [0, Tc-64]
    const int s_lo = (q0 >= win) ? 0 : ((win - q0 + 63) >> 6);
    const int kb_hi = min(Tc - 64, q0 + win);
    const int s_hi = (kb_hi - (q0 - win)) >> 6;          // inclusive

    for (int s = s_lo + wave; s <= s_hi; s += 4) {
        const int kb0 = q0 - win + s * 64;               // in [0, Tc-64]

        // S = Q K^T (64x64); K fragments direct from global (L2-resident)
        v4f sf[4][4];
        #pragma unroll
        for (int mi = 0; mi < 4; mi++)
            #pragma unroll
            for (int ni = 0; ni < 4; ni++) sf[mi][ni] = (v4f)(0.0f);
        #pragma unroll
        for (int ks = 0; ks < 2; ks++) {
            const int kc = ks * 32 + rq * 8;
            v8bf a[4], kf[4];
            #pragma unroll
            for (int mi = 0; mi < 4; mi++)
                a[mi] = *(const v8bf*)&sQ[(mi * 16 + cn) * SPAD + kc];
            #pragma unroll
            for (int ni = 0; ni < 4; ni++)
                kf[ni] = *(const v8bf*)(kp + (size_t)(kb0 + ni * 16 + cn) * Dc + kc);
            #pragma unroll
            for (int mi = 0; mi < 4; mi++)
                #pragma unroll
                for (int ni = 0; ni < 4; ni++)
                    sf[mi][ni] = __builtin_amdgcn_mfma_f32_16x16x32_bf16(
                        a[mi], kf[ni], sf[mi][ni], 0, 0, 0);
        }

        // p = exp2(clamp(s * log2e/8)); band mask only on edge subtiles
        const bool need_mask = (q0 + 63 - kb0 > win) || (kb0 + 63 - q0 > win);
        float psum[4][4];
        #pragma unroll
        for (int mi = 0; mi < 4; mi++)
            #pragma unroll
            for (int r = 0; r < 4; r++) psum[mi][r] = 0.0f;
        #pragma unroll
        for (int mi = 0; mi < 4; mi++)
            #pragma unroll
            for (int ni = 0; ni < 4; ni++)
                #pragma unroll
                for (int r = 0; r < 4; r++) {
                    float tt = sf[mi][ni][r] * C1;
                    if (need_mask) {
                        int qi = q0 + mi * 16 + rq * 4 + r;
                        int ki = kb0 + ni * 16 + cn;
                        int dd = qi - ki; dd = dd < 0 ? -dd : dd;
                        tt = (dd > win) ? -INFINITY : tt;
                    }
                    float p = exp2f(fminf(tt, 30.0f));   // masked -> 0
                    psum[mi][r] += p;
                    sP[wave][(mi * 16 + rq * 4 + r) * SPAD + ni * 16 + cn] = f2b(p);
                }
        #pragma unroll
        for (int mi = 0; mi < 4; mi++)
            #pragma unroll
            for (int r = 0; r < 4; r++) {
                #pragma unroll
                for (int off = 1; off < 16; off <<= 1)
                    psum[mi][r] += __shfl_xor(psum[mi][r], off, 16);
                l_i[mi][r] += psum[mi][r];
            }

        // O += P V  (A = P [q][k] from sP; B = V^T [hd][k] direct from Vt)
        #pragma unroll
        for (int ks = 0; ks < 2; ks++) {
            const int kc = ks * 32 + rq * 8;
            v8bf pa[4], vf[4];
            #pragma unroll
            for (int mi = 0; mi < 4; mi++)
                pa[mi] = *(const v8bf*)&sP[wave][(mi * 16 + cn) * SPAD + kc];
            #pragma unroll
            for (int nh = 0; nh < 4; nh++)
                vf[nh] = *(const v8bf*)(vtp + (size_t)(nh * 16 + cn) * Tc + kb0 + kc);
            #pragma unroll
            for (int mi = 0; mi < 4; mi++)
                #pragma unroll
                for (int nh = 0; nh < 4; nh++)
                    acc_o[mi][nh] = __builtin_amdgcn_mfma_f32_16x16x32_bf16(
                        pa[mi], vf[nh], acc_o[mi][nh], 0, 0, 0);
        }
    }

    // ---- merge: plain sums of per-wave (l, O) ----
    if (cn == 0) {
        #pragma unroll
        for (int mi = 0; mi < 4; mi++)
            #pragma unroll
            for (int r = 0; r < 4; r++)
                sL[wave][mi * 16 + rq * 4 + r] = l_i[mi][r];
    }
    __syncthreads();
    float* oacc = (float*)&sP[0][0];   // 16 KB: overlays sP[0..1] (dead)
    if (t < 64) {
        float Lv = sL[0][t] + sL[1][t] + sL[2][t] + sL[3][t];
        sLf[t] = (Lv > 0.0f) ? 1.0f / Lv : 0.0f;
    }
    #pragma unroll
    for (int w = 0; w < 4; w++) {
        if (wave == w) {
            #pragma unroll
            for (int mi = 0; mi < 4; mi++)
                #pragma unroll
                for (int r = 0; r < 4; r++) {
                    int row = mi * 16 + rq * 4 + r;
                    #pragma unroll
                    for (int nh = 0; nh < 4; nh++) {
                        float* p = &oacc[row * 64 + nh * 16 + cn];
                        if (w == 0) *p = acc_o[mi][nh][r];
                        else        *p += acc_o[mi][nh][r];
                    }
                }
        }
        __syncthreads();
    }
    bf16* ob = o + ((size_t)b * Tc + q0) * Dc + h * HDc;
    for (int i = t; i < 4096; i += 256) {
        int row = i >> 6, col = i & 63;
        ob[(size_t)row * Dc + col] = f2b(oacc[i] * sLf[row]);
    }
}

// ---------------------------------------------------------------- launch
extern "C" void kernel_launch(void* const* d_in, const int* in_sizes, int n_in,
                              void* d_out, int out_size, void* d_ws, size_t ws_size,
                              hipStream_t stream)
{
    const float* x     = (const float*)d_in[0];
    const float* inw   = (const float*)d_in[1];
    const float* inb   = (const float*)d_in[2];
    const float* outw  = (const float*)d_in[3];
    const float* outb  = (const float*)d_in[4];
    const float* w1    = (const float*)d_in[5];
    const float* b1    = (const float*)d_in[6];
    const float* w2    = (const float*)d_in[7];
    const float* b2    = (const float*)d_in[8];
    const float* ln1g  = (const float*)d_in[9];
    const float* ln1b  = (const float*)d_in[10];
    const float* ln2g  = (const float*)d_in[11];
    const float* ln2b  = (const float*)d_in[12];
    const int*   winp  = (const int*)d_in[13];
    float* out = (float*)d_out;   // fp32 [8192][768]; holds x1 mid-pipeline

    // Workspace (55.05 MB needed; >=62.9 MB proven available)
    char* ws = (char*)d_ws;
    constexpr size_t A_OFF   = 0;
    constexpr size_t QKV_OFF = (size_t)BTc * Dc * 2;                   // 12582912
    constexpr size_t WA_OFF  = QKV_OFF + 3 * (size_t)BTc * Dc * 2;     // 50331648
    constexpr size_t WS_NEED = WA_OFF + (size_t)(QKVc + Dc) * Dc * 2;  // 55050240
    if (ws_size < WS_NEED) return;

    bf16*  xn     = (bf16*)(ws + A_OFF);            // xn1 / obuf / xn2
    bf16*  qkvb   = (bf16*)(ws + QKV_OFF);          // Qb|Kb|Vt triple
    bf16*  Qb     = qkvb;
    bf16*  Kb     = qkvb + (size_t)BTc * Dc;
    bf16*  Vt     = qkvb + 2 * (size_t)BTc * Dc;
    bf16*  hbuf   = (bf16*)(ws + QKV_OFF);          // phase B
    bf16*  wmlp   = (bf16*)(ws + QKV_OFF + (size_t)BTc * (2 * Dc) * 2);
    bf16*  w1_b   = wmlp;
    bf16*  w2_b   = wmlp + (size_t)MLPc * Dc;
    bf16*  wqkv_b = (bf16*)(ws + WA_OFF);
    bf16*  wout_b = wqkv_b + (size_t)QKVc * Dc;

    constexpr int HALF = MLPc / 2;  // 1536

    // phase-A weight conversion
    cvt_kernel<<<(QKVc * Dc / 4 + 255) / 256, 256, 0, stream>>>(inw, wqkv_b, QKVc * Dc / 4);
    cvt_kernel<<<(Dc * Dc / 4 + 255) / 256, 256, 0, stream>>>(outw, wout_b, Dc * Dc / 4);

    // 1. LN1 (fp32 x -> bf16 xn)
    ln_kernel<<<BTc, 256, 0, stream>>>(x, ln1g, ln1b, xn);
    // 2. qkv GEMM with split-store epilogue -> Qb | Kb | Vt(transposed)
    gemm_bt<EPI_QKV, 128><<<dim3(QKVc / 128, BTc / 128), 256, 0, stream>>>(
        xn, wqkv_b, inb, qkvb, nullptr, nullptr, BTc, QKVc, Dc, Dc, Dc);
    // 3. banded attention (4-wave K-split, XCD-local grid) -> obuf (= xn)
    attn_kernel<<<dim3(Bc * Hc, Tc / 64), 256, 0, stream>>>(Qb, Kb, Vt, xn, winp);
    // 4. out(x1) = x + obuf @ out_w^T + out_b   (fp32, fused residual; TN=64)
    gemm_bt<EPI_RESID_F32, 64><<<dim3(Dc / 64, BTc / 128), 256, 0, stream>>>(
        xn, wout_b, outb, nullptr, out, x, BTc, Dc, Dc, Dc, Dc);
    // 5. LN2 (d_out fp32 -> bf16 xn2)
    ln_kernel<<<BTc, 256, 0, stream>>>(out, ln2g, ln2b, xn);
    // phase-B weight conversion (overlays dead Vt region)
    cvt_kernel<<<(MLPc * Dc / 4 + 255) / 256, 256, 0, stream>>>(w1, w1_b, MLPc * Dc / 4);
    cvt_kernel<<<(Dc * MLPc / 4 + 255) / 256, 256, 0, stream>>>(w2, w2_b, Dc * MLPc / 4);

    // 6/7. MLP in two 1536-wide halves; d_out holds x1, accumulate onto it
    for (int c = 0; c < 2; c++) {
        const bf16* w1c = w1_b + (size_t)c * HALF * Dc;   // rows [c*1536, ..)
        const bf16* w2c = w2_b + (size_t)c * HALF;        // cols [c*1536, ..)
        gemm_bt<EPI_GELU_BF16, 128><<<dim3(HALF / 128, BTc / 128), 256, 0, stream>>>(
            xn, w1c, b1 + c * HALF, hbuf, nullptr, nullptr, BTc, HALF, Dc, Dc, Dc);
        // down-proj: A = hbuf [8192][HALF], TN=64 for occupancy
        gemm_bt<EPI_ACC_F32, 64><<<dim3(Dc / 64, BTc / 128), 256, 0, stream>>>(
            hbuf, w2c, (c == 0) ? b2 : nullptr, nullptr, out, nullptr,
            BTc, Dc, HALF, HALF, MLPc);
    }
}

// Round 9
// 381.495 us; speedup vs baseline: 1.5110x; 1.0049x over previous
//
#include <hip/hip_runtime.h>
#include <hip/hip_bf16.h>

typedef __bf16 bf16;
typedef __bf16 v8bf __attribute__((ext_vector_type(8)));
typedef __bf16 v4bf __attribute__((ext_vector_type(4)));
typedef float  v4f  __attribute__((ext_vector_type(4)));

#define DEVI __device__ __forceinline__

constexpr int Bc   = 4;
constexpr int Tc   = 2048;
constexpr int Dc   = 768;
constexpr int Hc   = 12;
constexpr int HDc  = 64;
constexpr int MLPc = 3072;
constexpr int QKVc = 2304;    // 3*D
constexpr int BTc  = Bc * Tc; // 8192 rows
constexpr int SPAD = 72;      // LDS row stride: 144B = 36 banks

DEVI float b2f(bf16 x) { return (float)x; }
DEVI bf16  f2b(float x) { return (bf16)x; }

// async global->LDS, 16B per lane; lds dest = wave-uniform base + lane*16
#define GLDS(gp, lp) __builtin_amdgcn_global_load_lds( \
    (const __attribute__((address_space(1))) void*)(gp), \
    (__attribute__((address_space(3))) void*)(lp), 16, 0, 0)

// ---------------------------------------------------------------- fp32 -> bf16 conversion (two arrays per dispatch)
__global__ __launch_bounds__(256) void cvt2_kernel(
    const float* __restrict__ s0, bf16* __restrict__ d0, int n0,
    const float* __restrict__ s1, bf16* __restrict__ d1)
{
    int i = blockIdx.x * 256 + threadIdx.x;
    const float* s; bf16* d; int j;
    if (i < n0) { s = s0; d = d0; j = i; }
    else        { s = s1; d = d1; j = i - n0; }
    float4 v = ((const float4*)s)[j];
    v4bf o = { f2b(v.x), f2b(v.y), f2b(v.z), f2b(v.w) };
    ((v4bf*)d)[j] = o;
}

// ---------------------------------------------------------------- LayerNorm (fp32 in, bf16 out)
__global__ __launch_bounds__(256) void ln_kernel(
    const float* __restrict__ x, const float* __restrict__ g,
    const float* __restrict__ bt, bf16* __restrict__ out)
{
    const int row = blockIdx.x;
    const int t = threadIdx.x;
    const float* xr = x + (size_t)row * Dc;
    float v[3];
    v[0] = xr[t];
    v[1] = xr[t + 256];
    v[2] = xr[t + 512];
    float s = v[0] + v[1] + v[2];
    float s2 = v[0]*v[0] + v[1]*v[1] + v[2]*v[2];
    #pragma unroll
    for (int off = 32; off > 0; off >>= 1) {
        s  += __shfl_down(s, off);
        s2 += __shfl_down(s2, off);
    }
    __shared__ float red[8];
    const int wave = t >> 6, lane = t & 63;
    if (lane == 0) { red[wave] = s; red[4 + wave] = s2; }
    __syncthreads();
    s  = red[0] + red[1] + red[2] + red[3];
    s2 = red[4] + red[5] + red[6] + red[7];
    const float mean = s * (1.0f / Dc);
    const float var  = s2 * (1.0f / Dc) - mean * mean;
    const float rstd = rsqrtf(var + 1e-5f);
    bf16* orow = out + (size_t)row * Dc;
    #pragma unroll
    for (int i = 0; i < 3; i++) {
        int c = t + i * 256;
        orow[c] = f2b((v[i] - mean) * rstd * g[c] + bt[c]);
    }
}

// ---------------------------------------------------------------- GEMM (C = A @ B^T + bias, fused epilogues)
// A: [M][lda] bf16 row-major; Bw: [N rows][ldb] bf16, K columns used.
// TN = 128 (4 waves of 64x64) or 64 (4 waves of 32x64).
// XCD stripe swizzle + XOR LDS swizzle. EPI_QKV (TN=128): split-store Q|K|Vt.
enum { EPI_QKV = 0, EPI_GELU_BF16 = 1, EPI_RESID_F32 = 2, EPI_ACC_F32 = 3 };

template <int EPI, int TN>
__global__ __launch_bounds__(256) void gemm_bt(
    const bf16* __restrict__ A, const bf16* __restrict__ Bw,
    const float* __restrict__ bias,
    bf16* __restrict__ Cb, float* __restrict__ Cf,
    const float* __restrict__ resf,
    int M, int N, int K, int lda, int ldb)
{
    constexpr int MI = (TN == 128) ? 4 : 2;      // 16-row blocks per wave (m)
    __shared__ __align__(16) bf16 sA[128 * 64];
    __shared__ __align__(16) bf16 sB[TN * 64];
    const int t = threadIdx.x, wave = t >> 6, lane = t & 63;
    const int moff = (TN == 128) ? (wave & 1) * 64 : wave * 32;
    const int noff = (TN == 128) ? (wave >> 1) * 64 : 0;
    // XCD stripe swizzle (ny divisible by 8 for all our shapes)
    const int nx = gridDim.x, ny = gridDim.y;
    const int bid = blockIdx.y * nx + blockIdx.x;
    const int xcd = bid & 7, kk = bid >> 3;
    const int m0 = (xcd * (ny >> 3) + kk / nx) * 128;
    const int n0 = (kk % nx) * TN;
    const bf16* Ag = A + (size_t)m0 * lda;
    const bf16* Bg = Bw + (size_t)n0 * ldb;

    v4f acc[MI][4];
    #pragma unroll
    for (int i = 0; i < MI; i++)
        #pragma unroll
        for (int j = 0; j < 4; j++) acc[i][j] = (v4f)(0.0f);

    for (int k0 = 0; k0 < K; k0 += 64) {
        // stage with XOR swizzle: LDS slot c holds global chunk (c&7)^(r&7)
        #pragma unroll
        for (int i = 0; i < 4; i++) {
            int c = i * 256 + t;
            int r = c >> 3, j = (c & 7) ^ (r & 7);
            GLDS(Ag + (size_t)r * lda + k0 + j * 8,
                 &sA[(i * 256 + wave * 64) * 8]);
        }
        #pragma unroll
        for (int i = 0; i < TN / 32; i++) {
            int c = i * 256 + t;
            int r = c >> 3, j = (c & 7) ^ (r & 7);
            GLDS(Bg + (size_t)r * ldb + k0 + j * 8,
                 &sB[(i * 256 + wave * 64) * 8]);
        }
        __syncthreads();
        #pragma unroll
        for (int ks = 0; ks < 2; ks++) {
            const int rq = lane >> 4, rl = lane & 15;
            v8bf a[MI], b[4];
            #pragma unroll
            for (int mi = 0; mi < MI; mi++) {
                const int row = moff + mi * 16 + rl;
                a[mi] = *(const v8bf*)&sA[row * 64 + ((ks * 4 + rq) ^ (row & 7)) * 8];
            }
            #pragma unroll
            for (int ni = 0; ni < 4; ni++) {
                const int row = noff + ni * 16 + rl;
                b[ni] = *(const v8bf*)&sB[row * 64 + ((ks * 4 + rq) ^ (row & 7)) * 8];
            }
            #pragma unroll
            for (int mi = 0; mi < MI; mi++)
                #pragma unroll
                for (int ni = 0; ni < 4; ni++)
                    acc[mi][ni] = __builtin_amdgcn_mfma_f32_16x16x32_bf16(
                        a[mi], b[ni], acc[mi][ni], 0, 0, 0);
        }
        __syncthreads();
    }

    const int rq = lane >> 4, cn = lane & 15;
    #pragma unroll
    for (int mi = 0; mi < MI; mi++)
        #pragma unroll
        for (int ni = 0; ni < 4; ni++) {
            const int col = n0 + noff + ni * 16 + cn;
            const float bv = bias ? bias[col] : 0.0f;
            if constexpr (EPI == EPI_QKV) {
                const int row0 = m0 + moff + mi * 16 + rq * 4;
                if (n0 < 2 * Dc) {
                    bf16* dst = Cb + (col < Dc ? 0 : (size_t)BTc * Dc);
                    const int cadj = col < Dc ? col : col - Dc;
                    #pragma unroll
                    for (int r = 0; r < 4; r++)
                        dst[(size_t)(row0 + r) * Dc + cadj] = f2b(acc[mi][ni][r] + bv);
                } else {
                    const int vcol = col - 2 * Dc;
                    const int hh = vcol >> 6, hd = vcol & 63;
                    const int bb = row0 >> 11, t0 = row0 & 2047;
                    v4bf pk;
                    #pragma unroll
                    for (int r = 0; r < 4; r++) pk[r] = f2b(acc[mi][ni][r] + bv);
                    *(v4bf*)(Cb + 2 * (size_t)BTc * Dc +
                             (((size_t)bb * Hc + hh) * HDc + hd) * Tc + t0) = pk;
                }
            } else {
                #pragma unroll
                for (int r = 0; r < 4; r++) {
                    const int row = m0 + moff + mi * 16 + rq * 4 + r;
                    const size_t idx = (size_t)row * N + col;
                    float vv = acc[mi][ni][r] + bv;
                    if constexpr (EPI == EPI_GELU_BF16) {
                        Cb[idx] = f2b(0.5f * vv * (1.0f + erff(vv * 0.70710678118f)));
                    } else if constexpr (EPI == EPI_RESID_F32) {
                        Cf[idx] = vv + resf[idx];
                    } else {  // EPI_ACC_F32: sequential RMW accumulate
                        Cf[idx] = vv + Cf[idx];
                    }
                }
            }
        }
}

// ---------------------------------------------------------------- Banded flash attention
// 4-wave K-split per (q-tile, head); no-max softmax (exact: shift-invariant,
// scores bounded so exp2 clamp at 2^30 can't overflow fp32 sums).
// l computed by MFMA with all-ones B (row-sum of bf16 P) — no shuffle reduce.
// grid = (bh=48, qt=32): 48%8==0 => all q-tiles of one bh on one XCD.
__global__ __launch_bounds__(256, 2) void attn_kernel(
    const bf16* __restrict__ Qb, const bf16* __restrict__ Kb,
    const bf16* __restrict__ Vt, bf16* __restrict__ o,
    const int* __restrict__ winp)
{
    const int bh = blockIdx.x, qt = blockIdx.y;
    const int b = bh / Hc, h = bh % Hc;
    const int q0 = qt * 64;
    const int win = *winp;
    const int t = threadIdx.x, wave = t >> 6, lane = t & 63;
    const int rq = lane >> 4, cn = lane & 15;
    constexpr float C1 = 0.125f * 1.44269504089f;   // log2(e)/8

    __shared__ __align__(16) bf16 sQ[64 * SPAD];
    __shared__ __align__(16) bf16 sP[4][64 * SPAD];
    __shared__ float sL[4][64], sLf[64];

    const bf16* qp  = Qb + ((size_t)b * Tc + q0) * Dc + h * HDc;
    const bf16* kp  = Kb + ((size_t)b * Tc) * Dc + h * HDc;
    const bf16* vtp = Vt + (size_t)bh * HDc * Tc;

    // stage Q tile [64 rows][64 cols] cooperatively (256 threads, 2x16B each)
    #pragma unroll
    for (int i = 0; i < 2; i++) {
        int c = i * 256 + t;
        int r = c >> 3, c8 = (c & 7) * 8;
        *(uint4*)&sQ[r * SPAD + c8] = *(const uint4*)(qp + (size_t)r * Dc + c8);
    }
    __syncthreads();

    v4f acc_o[4][4], acc_l[4];
    #pragma unroll
    for (int mi = 0; mi < 4; mi++) {
        acc_l[mi] = (v4f)(0.0f);
        #pragma unroll
        for (int j = 0; j < 4; j++) acc_o[mi][j] = (v4f)(0.0f);
    }
    v8bf vones;
    #pragma unroll
    for (int j = 0; j < 8; j++) vones[j] = f2b(1.0f);

    // key subtiles kb0 = q0 - win + s*64, constrained to [0, Tc-64]
    const int s_lo = (q0 >= win) ? 0 : ((win - q0 + 63) >> 6);
    const int kb_hi = min(Tc - 64, q0 + win);
    const int s_hi = (kb_hi - (q0 - win)) >> 6;          // inclusive

    for (int s = s_lo + wave; s <= s_hi; s += 4) {
        const int kb0 = q0 - win + s * 64;               // in [0, Tc-64]

        // S = Q K^T (64x64); K fragments direct from global (L2-resident)
        v4f sf[4][4];
        #pragma unroll
        for (int mi = 0; mi < 4; mi++)
            #pragma unroll
            for (int ni = 0; ni < 4; ni++) sf[mi][ni] = (v4f)(0.0f);
        #pragma unroll
        for (int ks = 0; ks < 2; ks++) {
            const int kc = ks * 32 + rq * 8;
            v8bf a[4], kf[4];
            #pragma unroll
            for (int mi = 0; mi < 4; mi++)
                a[mi] = *(const v8bf*)&sQ[(mi * 16 + cn) * SPAD + kc];
            #pragma unroll
            for (int ni = 0; ni < 4; ni++)
                kf[ni] = *(const v8bf*)(kp + (size_t)(kb0 + ni * 16 + cn) * Dc + kc);
            #pragma unroll
            for (int mi = 0; mi < 4; mi++)
                #pragma unroll
                for (int ni = 0; ni < 4; ni++)
                    sf[mi][ni] = __builtin_amdgcn_mfma_f32_16x16x32_bf16(
                        a[mi], kf[ni], sf[mi][ni], 0, 0, 0);
        }

        // p = exp2(clamp(s * log2e/8)); band mask only on edge subtiles
        const bool need_mask = (q0 + 63 - kb0 > win) || (kb0 + 63 - q0 > win);
        #pragma unroll
        for (int mi = 0; mi < 4; mi++)
            #pragma unroll
            for (int ni = 0; ni < 4; ni++)
                #pragma unroll
                for (int r = 0; r < 4; r++) {
                    float tt = sf[mi][ni][r] * C1;
                    if (need_mask) {
                        int qi = q0 + mi * 16 + rq * 4 + r;
                        int ki = kb0 + ni * 16 + cn;
                        int dd = qi - ki; dd = dd < 0 ? -dd : dd;
                        tt = (dd > win) ? -INFINITY : tt;
                    }
                    float p = exp2f(fminf(tt, 30.0f));   // masked -> 0
                    sP[wave][(mi * 16 + rq * 4 + r) * SPAD + ni * 16 + cn] = f2b(p);
                }

        // O += P V; l += P 1  (A = P from sP; B = V^T direct from Vt / ones)
        #pragma unroll
        for (int ks = 0; ks < 2; ks++) {
            const int kc = ks * 32 + rq * 8;
            v8bf pa[4], vf[4];
            #pragma unroll
            for (int mi = 0; mi < 4; mi++)
                pa[mi] = *(const v8bf*)&sP[wave][(mi * 16 + cn) * SPAD + kc];
            #pragma unroll
            for (int nh = 0; nh < 4; nh++)
                vf[nh] = *(const v8bf*)(vtp + (size_t)(nh * 16 + cn) * Tc + kb0 + kc);
            #pragma unroll
            for (int mi = 0; mi < 4; mi++)
                acc_l[mi] = __builtin_amdgcn_mfma_f32_16x16x32_bf16(
                    pa[mi], vones, acc_l[mi], 0, 0, 0);
            #pragma unroll
            for (int mi = 0; mi < 4; mi++)
                #pragma unroll
                for (int nh = 0; nh < 4; nh++)
                    acc_o[mi][nh] = __builtin_amdgcn_mfma_f32_16x16x32_bf16(
                        pa[mi], vf[nh], acc_o[mi][nh], 0, 0, 0);
        }
    }

    // ---- merge: plain sums of per-wave (l, O) ----
    if (cn == 0) {
        #pragma unroll
        for (int mi = 0; mi < 4; mi++)
            #pragma unroll
            for (int r = 0; r < 4; r++)
                sL[wave][mi * 16 + rq * 4 + r] = acc_l[mi][r];
    }
    __syncthreads();
    float* oacc = (float*)&sP[0][0];   // 16 KB: overlays sP[0..1] (dead)
    if (t < 64) {
        float Lv = sL[0][t] + sL[1][t] + sL[2][t] + sL[3][t];
        sLf[t] = (Lv > 0.0f) ? 1.0f / Lv : 0.0f;
    }
    #pragma unroll
    for (int w = 0; w < 4; w++) {
        if (wave == w) {
            #pragma unroll
            for (int mi = 0; mi < 4; mi++)
                #pragma unroll
                for (int r = 0; r < 4; r++) {
                    int row = mi * 16 + rq * 4 + r;
                    #pragma unroll
                    for (int nh = 0; nh < 4; nh++) {
                        float* p = &oacc[row * 64 + nh * 16 + cn];
                        if (w == 0) *p = acc_o[mi][nh][r];
                        else        *p += acc_o[mi][nh][r];
                    }
                }
        }
        __syncthreads();
    }
    bf16* ob = o + ((size_t)b * Tc + q0) * Dc + h * HDc;
    for (int i = t; i < 4096; i += 256) {
        int row = i >> 6, col = i & 63;
        ob[(size_t)row * Dc + col] = f2b(oacc[i] * sLf[row]);
    }
}

// ---------------------------------------------------------------- launch
extern "C" void kernel_launch(void* const* d_in, const int* in_sizes, int n_in,
                              void* d_out, int out_size, void* d_ws, size_t ws_size,
                              hipStream_t stream)
{
    const float* x     = (const float*)d_in[0];
    const float* inw   = (const float*)d_in[1];
    const float* inb   = (const float*)d_in[2];
    const float* outw  = (const float*)d_in[3];
    const float* outb  = (const float*)d_in[4];
    const float* w1    = (const float*)d_in[5];
    const float* b1    = (const float*)d_in[6];
    const float* w2    = (const float*)d_in[7];
    const float* b2    = (const float*)d_in[8];
    const float* ln1g  = (const float*)d_in[9];
    const float* ln1b  = (const float*)d_in[10];
    const float* ln2g  = (const float*)d_in[11];
    const float* ln2b  = (const float*)d_in[12];
    const int*   winp  = (const int*)d_in[13];
    float* out = (float*)d_out;   // fp32 [8192][768]; holds x1 mid-pipeline

    // Workspace (55.05 MB needed; >=62.9 MB proven available)
    char* ws = (char*)d_ws;
    constexpr size_t A_OFF   = 0;
    constexpr size_t QKV_OFF = (size_t)BTc * Dc * 2;                   // 12582912
    constexpr size_t WA_OFF  = QKV_OFF + 3 * (size_t)BTc * Dc * 2;     // 50331648
    constexpr size_t WS_NEED = WA_OFF + (size_t)(QKVc + Dc) * Dc * 2;  // 55050240
    if (ws_size < WS_NEED) return;

    bf16*  xn     = (bf16*)(ws + A_OFF);            // xn1 / obuf / xn2
    bf16*  qkvb   = (bf16*)(ws + QKV_OFF);          // Qb|Kb|Vt triple
    bf16*  Qb     = qkvb;
    bf16*  Kb     = qkvb + (size_t)BTc * Dc;
    bf16*  Vt     = qkvb + 2 * (size_t)BTc * Dc;
    bf16*  hbuf   = (bf16*)(ws + QKV_OFF);          // phase B
    bf16*  wmlp   = (bf16*)(ws + QKV_OFF + (size_t)BTc * (2 * Dc) * 2);
    bf16*  w1_b   = wmlp;
    bf16*  w2_b   = wmlp + (size_t)MLPc * Dc;
    bf16*  wqkv_b = (bf16*)(ws + WA_OFF);
    bf16*  wout_b = wqkv_b + (size_t)QKVc * Dc;

    constexpr int HALF = MLPc / 2;  // 1536
    constexpr int NQKV4 = QKVc * Dc / 4, NOUT4 = Dc * Dc / 4;
    constexpr int NW14  = MLPc * Dc / 4, NW24  = Dc * MLPc / 4;

    // phase-A weight conversion (one dispatch)
    cvt2_kernel<<<(NQKV4 + NOUT4) / 256, 256, 0, stream>>>(
        inw, wqkv_b, NQKV4, outw, wout_b);

    // 1. LN1 (fp32 x -> bf16 xn)
    ln_kernel<<<BTc, 256, 0, stream>>>(x, ln1g, ln1b, xn);
    // 2. qkv GEMM with split-store epilogue -> Qb | Kb | Vt(transposed)
    gemm_bt<EPI_QKV, 128><<<dim3(QKVc / 128, BTc / 128), 256, 0, stream>>>(
        xn, wqkv_b, inb, qkvb, nullptr, nullptr, BTc, QKVc, Dc, Dc, Dc);
    // 3. banded attention (4-wave K-split, XCD-local grid) -> obuf (= xn)
    attn_kernel<<<dim3(Bc * Hc, Tc / 64), 256, 0, stream>>>(Qb, Kb, Vt, xn, winp);
    // phase-B weight conversion (Vt region dead after attention; one dispatch)
    cvt2_kernel<<<(NW14 + NW24) / 256, 256, 0, stream>>>(
        w1, w1_b, NW14, w2, w2_b);
    // 4. out(x1) = x + obuf @ out_w^T + out_b   (fp32, fused residual; TN=64)
    gemm_bt<EPI_RESID_F32, 64><<<dim3(Dc / 64, BTc / 128), 256, 0, stream>>>(
        xn, wout_b, outb, nullptr, out, x, BTc, Dc, Dc, Dc, Dc);
    // 5. LN2 (d_out fp32 -> bf16 xn2)
    ln_kernel<<<BTc, 256, 0, stream>>>(out, ln2g, ln2b, xn);

    // 6/7. MLP in two 1536-wide halves; d_out holds x1, accumulate onto it
    for (int c = 0; c < 2; c++) {
        const bf16* w1c = w1_b + (size_t)c * HALF * Dc;   // rows [c*1536, ..)
        const bf16* w2c = w2_b + (size_t)c * HALF;        // cols [c*1536, ..)
        gemm_bt<EPI_GELU_BF16, 128><<<dim3(HALF / 128, BTc / 128), 256, 0, stream>>>(
            xn, w1c, b1 + c * HALF, hbuf, nullptr, nullptr, BTc, HALF, Dc, Dc, Dc);
        // down-proj: A = hbuf [8192][HALF], TN=64 for occupancy
        gemm_bt<EPI_ACC_F32, 64><<<dim3(Dc / 64, BTc / 128), 256, 0, stream>>>(
            hbuf, w2c, (c == 0) ? b2 : nullptr, nullptr, out, nullptr,
            BTc, Dc, HALF, HALF, MLPc);
    }
}